// Round 2
// baseline (249.456 us; speedup 1.0000x reference)
//
#include <hip/hip_runtime.h>
#include <hip/hip_bf16.h>
#include <math.h>

typedef short bf16x8 __attribute__((ext_vector_type(8)));
typedef float f32x4 __attribute__((ext_vector_type(4)));
typedef unsigned short u16;

__device__ inline float b2f(u16 h) {
    unsigned int u = ((unsigned int)h) << 16;
    float f;
    __builtin_memcpy(&f, &u, 4);
    return f;
}

__device__ inline u16 f2b(float f) {
    unsigned int u;
    __builtin_memcpy(&u, &f, 4);
    unsigned int lsb = (u >> 16) & 1u;
    u += 0x7fffu + lsb;
    return (u16)(u >> 16);
}

// async 16B global -> LDS (wave-uniform base + lane*16 at all call sites)
__device__ __forceinline__ void gl2lds16(const u16* g, u16* l) {
    __builtin_amdgcn_global_load_lds(
        (const __attribute__((address_space(1))) unsigned int*)g,
        (__attribute__((address_space(3))) unsigned int*)l,
        16, 0, 0);
}

#define PITCH 72   // wtrans scratch pitch

// log2(e) / 8  (softmax temperature sqrt(64)=8 folded into Q projection)
#define QSCALE 0.18033688011112042f

// ---------------------------------------------------------------------------
// Prep A: x f32 -> bf16
// ---------------------------------------------------------------------------
__global__ __launch_bounds__(256) void cvt_kernel(const float* __restrict__ x,
                                                  u16* __restrict__ xb) {
    int idx = blockIdx.x * 256 + threadIdx.x;   // 2,097,152 float4s
    float4 v = ((const float4*)x)[idx];
    ushort4 o;
    o.x = f2b(v.x); o.y = f2b(v.y); o.z = f2b(v.z); o.w = f2b(v.w);
    ((ushort4*)xb)[idx] = o;
}

// ---------------------------------------------------------------------------
// Prep B: transpose+convert four 512x512 f32 weights into bf16 WT[n][k].
// Order: q, k, v, o (k and v adjacent -> fused KV GEMM sees 1024 N-rows).
// ---------------------------------------------------------------------------
__global__ __launch_bounds__(256) void wtrans_kernel(const float* __restrict__ w0,
                                                     const float* __restrict__ w1,
                                                     const float* __restrict__ w2,
                                                     const float* __restrict__ w3,
                                                     u16* __restrict__ wt) {
    const float* W = blockIdx.z == 0 ? w0 : blockIdx.z == 1 ? w1
                   : blockIdx.z == 2 ? w2 : w3;
    u16* WT = wt + (size_t)blockIdx.z * 262144;
    __shared__ u16 T[64 * PITCH];
    int tid = threadIdx.x;
    int nB = blockIdx.x * 64, kB = blockIdx.y * 64;
#pragma unroll
    for (int t = 0; t < 4; ++t) {
        int e = tid + t * 256;
        int r = e >> 4, c4 = (e & 15) * 4;
        float4 v = *(const float4*)(&W[(size_t)(kB + r) * 512 + nB + c4]);
        u16* dst = &T[r * PITCH + c4];
        dst[0] = f2b(v.x); dst[1] = f2b(v.y); dst[2] = f2b(v.z); dst[3] = f2b(v.w);
    }
    __syncthreads();
    int n = tid & 63, kg = tid >> 6;
#pragma unroll
    for (int p = 0; p < 2; ++p) {
        int k0 = (kg + p * 4) * 8;
        u16 tmp[8];
#pragma unroll
        for (int i = 0; i < 8; ++i) tmp[i] = T[(k0 + i) * PITCH + n];
        *(int4*)(&WT[(size_t)(nB + n) * 512 + kB + k0]) = *(int4*)tmp;
    }
}

// ---------------------------------------------------------------------------
// Kernel 1: TF avg-pool 3x3/s2 SAME (divide by valid count), bf16 in/out.
// Vectorized: one thread = 8 channels (b128 loads/stores).
// ---------------------------------------------------------------------------
__global__ __launch_bounds__(256) void pool_kernel(const u16* __restrict__ xb,
                                                   u16* __restrict__ xp) {
    int idx = blockIdx.x * 256 + threadIdx.x;   // 262,144 = (4,32,32,64)
    int c8 = idx & 63;
    int j = (idx >> 6) & 31;
    int i = (idx >> 11) & 31;
    int b = idx >> 16;
    int r0 = 2 * i, c0 = 2 * j;
    int rmax = min(r0 + 3, 64), cmax = min(c0 + 3, 64);
    float acc[8] = {};
    for (int r = r0; r < rmax; ++r)
        for (int cc = c0; cc < cmax; ++cc) {
            bf16x8 v = *(const bf16x8*)(
                &xb[(size_t)((((b << 6) + r) << 6) + cc) * 512 + c8 * 8]);
#pragma unroll
            for (int t = 0; t < 8; ++t) acc[t] += b2f(((const u16*)&v)[t]);
        }
    float inv = 1.f / (float)((rmax - r0) * (cmax - c0));
    u16 o[8];
#pragma unroll
    for (int t = 0; t < 8; ++t) o[t] = f2b(acc[t] * inv);
    *(int4*)(&xp[(size_t)idx * 8]) = *(int4*)o;
}

// ---------------------------------------------------------------------------
// Kernel 2: m97-class GEMM. Tile 128x128, BK=64, 4 waves 2x2; global_load_lds
// into XOR-8 swizzled LDS. OM=0: bf16 row-major * oscale. OM=1: f32 + f32
// residual. OM=3: fused K|V (N=1024): cols<512 -> Kw row-major, cols>=512 ->
// V^T per-group layout into Cv2.
// ---------------------------------------------------------------------------
template <int OM>
__global__ __launch_bounds__(256, 2) void gemm_bf16(const u16* __restrict__ A,
                                                    const u16* __restrict__ WT,
                                                    const float* __restrict__ bias,
                                                    const float* __restrict__ bias2res,
                                                    void* __restrict__ Cv,
                                                    void* __restrict__ Cv2,
                                                    float oscale) {
    __shared__ __align__(16) u16 At[128 * 64];
    __shared__ __align__(16) u16 Bt[128 * 64];
    int tid = threadIdx.x, lane = tid & 63, wave = tid >> 6;
    int q = lane >> 4, l16 = lane & 15;
    int wm = wave & 1, wn = wave >> 1;
    int nBase = blockIdx.x * 128, mBase = blockIdx.y * 128;
    f32x4 acc[4][4] = {};

    for (int kk = 0; kk < 512; kk += 64) {
        __syncthreads();
#pragma unroll
        for (int t = 0; t < 4; ++t) {
            int c = wave * 64 + lane + t * 256;       // chunk slot 0..1023
            int m = c >> 3, kc = (c & 7) ^ (m & 7);   // source chunk for slot
            gl2lds16(&A[(size_t)(mBase + m) * 512 + kk + kc * 8], &At[c * 8]);
            gl2lds16(&WT[(size_t)(nBase + m) * 512 + kk + kc * 8], &Bt[c * 8]);
        }
        __syncthreads();
#pragma unroll
        for (int ds = 0; ds < 2; ++ds) {
            bf16x8 a[4], b[4];
#pragma unroll
            for (int i = 0; i < 4; ++i) {
                int ma = wm * 64 + i * 16 + l16;
                a[i] = *(bf16x8*)(&At[ma * 64 + ((((ds << 2) + q) ^ (ma & 7)) << 3)]);
                int nb = wn * 64 + i * 16 + l16;
                b[i] = *(bf16x8*)(&Bt[nb * 64 + ((((ds << 2) + q) ^ (nb & 7)) << 3)]);
            }
#pragma unroll
            for (int i = 0; i < 4; ++i)
#pragma unroll
                for (int j = 0; j < 4; ++j)
                    acc[i][j] = __builtin_amdgcn_mfma_f32_16x16x32_bf16(a[i], b[j], acc[i][j], 0, 0, 0);
        }
    }

    bool isK = (OM != 3) || (nBase < 512);
#pragma unroll
    for (int j = 0; j < 4; ++j) {
        int col = nBase + wn * 64 + j * 16 + l16;
        float bv;
        if constexpr (OM == 3) bv = isK ? bias[col] : bias2res[col - 512];
        else bv = bias[col];
#pragma unroll
        for (int i = 0; i < 4; ++i) {
#pragma unroll
            for (int r = 0; r < 4; ++r) {
                int row = mBase + wm * 64 + i * 16 + q * 4 + r;
                float v = acc[i][j][r] + bv;
                if constexpr (OM == 1) {
                    v += bias2res[(size_t)row * 512 + col];
                    ((float*)Cv)[(size_t)row * 512 + col] = v;
                } else if constexpr (OM == 0) {
                    ((u16*)Cv)[(size_t)row * 512 + col] = f2b(v * oscale);
                } else {
                    if (isK) {
                        ((u16*)Cv)[(size_t)row * 512 + col] = f2b(v);
                    } else {
                        int colv = col - 512;
                        int g = row >> 7, m2 = ((row & 127) << 3) + (colv >> 6), d = colv & 63;
                        ((u16*)Cv2)[(size_t)((g << 6) + d) * 1024 + m2] = f2b(v);
                    }
                }
            }
        }
    }
}

// ---------------------------------------------------------------------------
// Kernel 3: flash attention per group, S^T formulation, 64-m tiles,
// double-buffered K/V staging (stage t+1 issued BEFORE compute t so the
// vmcnt(0) the compiler emits at the barrier lands after ~2K cycles of
// compute -- latency hidden; was 8x fully-exposed drains).
// exp2 via raw v_exp_f32 builtin (no denormal fixup; |z| < 50).
// P->bf16 via v_cvt_pk_bf16_f32 (2 instrs vs 6, RNE rounding).
// LDS = 2x8K (K) + 2x8K (V^T) + 8K (Pt) = 40960 B -> 4 blocks/CU; grid 1024.
// kf transients NOT hoisted (VGPR budget 128/wave at occupancy 4).
// ---------------------------------------------------------------------------
__device__ __forceinline__ void attn_tile(const u16* KtB, const u16* VTsB,
                                          int* Pt32, const bf16x8 (&qf)[2][2],
                                          f32x4 (&oacc)[2][4], float (&rsum)[2],
                                          int q, int l16, int prow, int pkey) {
#pragma unroll
    for (int s = 0; s < 2; ++s) {
        // S^T block over 64 m: p = exp2(z); packed b64 write to Pt[n][m]
#pragma unroll
        for (int cb = 0; cb < 4; ++cb) {
            int m = cb * 16 + l16;            // m&7 == l16&7: key loop-invariant
            const u16* kr = &KtB[m * 64];
            bf16x8 kf0 = *(const bf16x8*)(kr + ((q ^ (l16 & 7)) << 3));
            bf16x8 kf1 = *(const bf16x8*)(kr + (((4 + q) ^ (l16 & 7)) << 3));
            f32x4 z = {};
            z = __builtin_amdgcn_mfma_f32_16x16x32_bf16(kf0, qf[s][0], z, 0, 0, 0);
            z = __builtin_amdgcn_mfma_f32_16x16x32_bf16(kf1, qf[s][1], z, 0, 0, 0);
            float p0 = __builtin_amdgcn_exp2f(z[0]);
            float p1 = __builtin_amdgcn_exp2f(z[1]);
            float p2 = __builtin_amdgcn_exp2f(z[2]);
            float p3 = __builtin_amdgcn_exp2f(z[3]);
            rsum[s] += (p0 + p1) + (p2 + p3);
            unsigned w0, w1;
            asm("v_cvt_pk_bf16_f32 %0, %1, %2" : "=v"(w0) : "v"(p0), "v"(p1));
            asm("v_cvt_pk_bf16_f32 %0, %1, %2" : "=v"(w1) : "v"(p2), "v"(p3));
            int2 w;
            w.x = (int)w0;
            w.y = (int)w1;
            int pd = (cb * 8 + q * 2) ^ pkey;
            *(int2*)(&Pt32[prow + pd]) = w;
        }
        // O += P V (same wave wrote Pt rows; DS in-order, no barrier)
#pragma unroll
        for (int ds = 0; ds < 2; ++ds) {
            int pd = (ds * 16 + q * 4) ^ pkey;
            bf16x8 ap = *(bf16x8*)(&Pt32[prow + pd]);
#pragma unroll
            for (int db = 0; db < 4; ++db) {
                int dd = db * 16 + l16;       // dd&7 == l16&7
                int jj = ds * 4 + q;
                bf16x8 vb = *(const bf16x8*)(&VTsB[dd * 64 + ((jj ^ (l16 & 7)) << 3)]);
                oacc[s][db] = __builtin_amdgcn_mfma_f32_16x16x32_bf16(ap, vb, oacc[s][db], 0, 0, 0);
            }
        }
    }
}

__global__ __launch_bounds__(256, 4) void attn_kernel(const u16* __restrict__ Q,
                                                      const u16* __restrict__ K,
                                                      const u16* __restrict__ VT_g,
                                                      u16* __restrict__ O) {
    int g = blockIdx.y;
    int qtile = blockIdx.x;   // 0..31
    const u16* Qg = Q + (size_t)g * 262144;
    const u16* Kg = K + (size_t)g * 65536;
    const u16* Vt = VT_g + (size_t)g * 65536;   // [d][m], pitch 1024
    u16* Og = O + (size_t)g * 262144;

    __shared__ __align__(16) u16 Kt[2][64 * 64];    // XOR-8 swizzled [m][d]
    __shared__ __align__(16) u16 VTs[2][64 * 64];   // XOR-8 swizzled [d][m]
    __shared__ __align__(16) u16 Pt[64 * 64];       // XOR-4dw swizzled [n][m]

    int tid = threadIdx.x, lane = tid & 63, wave = tid >> 6;
    int q = lane >> 4, l16 = lane & 15;
    int n0 = qtile * 128;
    int pkey = (l16 & 7) << 2;            // dword-XOR key for Pt
    int prow = (wave * 16 + l16) * 32;    // Pt row base (dwords)
    int* Pt32 = (int*)Pt;

    bf16x8 qf[2][2];
#pragma unroll
    for (int s = 0; s < 2; ++s)
#pragma unroll
        for (int ds = 0; ds < 2; ++ds)
            qf[s][ds] = *(const bf16x8*)(
                &Qg[(size_t)(n0 + s * 64 + wave * 16 + l16) * 64 + ds * 32 + q * 8]);

    f32x4 oacc[2][4] = {};
    float rsum[2] = {0.f, 0.f};

    // staging: 2 slots/thread each for K and V^T; tile = 64 m-rows (8 KB each)
    int c0 = tid, c1 = tid + 256;
    const u16* ks0 = Kg + ((c0 >> 3) * 64 + (((c0 ^ (c0 >> 3)) & 7) << 3));
    const u16* ks1 = Kg + ((c1 >> 3) * 64 + (((c1 ^ (c1 >> 3)) & 7) << 3));
    const u16* vs0 = Vt + ((c0 >> 3) * 1024 + (((c0 ^ (c0 >> 3)) & 7) << 3));
    const u16* vs1 = Vt + ((c1 >> 3) * 1024 + (((c1 ^ (c1 >> 3)) & 7) << 3));

    auto stage = [&](int buf) {
        gl2lds16(ks0, &Kt[buf][c0 * 8]);
        gl2lds16(ks1, &Kt[buf][c1 * 8]);
        gl2lds16(vs0, &VTs[buf][c0 * 8]);
        gl2lds16(vs1, &VTs[buf][c1 * 8]);
        ks0 += 4096; ks1 += 4096;   // next 64 K-rows
        vs0 += 64;   vs1 += 64;     // next 64 m-cols of V^T
    };

    stage(0);
    asm volatile("s_waitcnt vmcnt(0)" ::: "memory");
    __syncthreads();

#pragma unroll 1
    for (int tt = 0; tt < 8; ++tt) {
        stage(1);                     // loads for tile 2tt+1 in flight...
        attn_tile(&Kt[0][0], &VTs[0][0], Pt32, qf, oacc, rsum, q, l16, prow, pkey);
        asm volatile("s_waitcnt vmcnt(0)" ::: "memory");
        __syncthreads();              // ...landed under compute
        if (tt < 7) stage(0);         // loads for tile 2tt+2
        attn_tile(&Kt[1][0], &VTs[1][0], Pt32, qf, oacc, rsum, q, l16, prow, pkey);
        asm volatile("s_waitcnt vmcnt(0)" ::: "memory");
        __syncthreads();
    }

    // epilogue: rsum lives at row n=l16 (partial over quads) -> reduce over
    // quads, then fetch row (q*4+r)'s total via shfl, normalize, store.
#pragma unroll
    for (int s = 0; s < 2; ++s) {
        float v = rsum[s];
        v += __shfl_xor(v, 16, 64);
        v += __shfl_xor(v, 32, 64);
        rsum[s] = v;
    }
    float inv[2][4];
#pragma unroll
    for (int s = 0; s < 2; ++s)
#pragma unroll
        for (int r = 0; r < 4; ++r)
            inv[s][r] = 1.f / __shfl(rsum[s], q * 4 + r, 64);
#pragma unroll
    for (int s = 0; s < 2; ++s)
#pragma unroll
        for (int db = 0; db < 4; ++db)
#pragma unroll
            for (int r = 0; r < 4; ++r) {
                int row = n0 + s * 64 + wave * 16 + q * 4 + r;
                Og[(size_t)row * 64 + db * 16 + l16] = f2b(oacc[s][db][r] * inv[s][r]);
            }
}

// ---------------------------------------------------------------------------
extern "C" void kernel_launch(void* const* d_in, const int* in_sizes, int n_in,
                              void* d_out, int out_size, void* d_ws, size_t ws_size,
                              hipStream_t stream) {
    const float* x   = (const float*)d_in[0];
    const float* w_q = (const float*)d_in[1];
    const float* b_q = (const float*)d_in[2];
    const float* w_k = (const float*)d_in[3];
    const float* b_k = (const float*)d_in[4];
    const float* w_v = (const float*)d_in[5];
    const float* b_v = (const float*)d_in[6];
    const float* w_o = (const float*)d_in[7];
    const float* b_o = (const float*)d_in[8];
    float* out = (float*)d_out;

    char* ws = (char*)d_ws;
    u16* xb  = (u16*)(ws);                        // 16 MB (16384,512) bf16
    u16* xp  = (u16*)(ws + (16ull << 20));        //  4 MB (4096,512)
    u16* Qw  = (u16*)(ws + (20ull << 20));        // 16 MB (16384,512)
    u16* Kw  = (u16*)(ws + (36ull << 20));        //  4 MB (4096,512)
    u16* VwT = (u16*)(ws + (40ull << 20));        //  4 MB 32x(64,1024)
    u16* wT  = (u16*)(ws + (44ull << 20));        //  2 MB: 4 x 512x512 bf16
    u16* Ow  = xb;  // alias: xb's last reader (Q-GEMM) precedes attn's write

    cvt_kernel<<<8192, 256, 0, stream>>>(x, xb);
    wtrans_kernel<<<dim3(8, 8, 4), 256, 0, stream>>>(w_q, w_k, w_v, w_o, wT);
    pool_kernel<<<1024, 256, 0, stream>>>(xb, xp);
    // Q projection (scaled by log2(e)/8)
    gemm_bf16<0><<<dim3(4, 128), 256, 0, stream>>>(xb, wT, b_q, nullptr, Qw, nullptr, QSCALE);
    // fused K|V projection (N=1024 over adjacent K^T,V^T weights)
    gemm_bf16<3><<<dim3(8, 32), 256, 0, stream>>>(xp, wT + 262144, b_k, b_v, Kw, VwT, 1.0f);
    // attention: 32 q-tiles x 32 groups
    attn_kernel<<<dim3(32, 32), 256, 0, stream>>>(Qw, Kw, VwT, Ow);
    // output projection + f32 residual
    gemm_bf16<1><<<dim3(4, 128), 256, 0, stream>>>(Ow, wT + 786432, b_o, x, out, nullptr, 1.0f);
}

// Round 3
// 224.577 us; speedup vs baseline: 1.1108x; 1.1108x over previous
//
#include <hip/hip_runtime.h>
#include <hip/hip_bf16.h>
#include <math.h>

typedef short bf16x8 __attribute__((ext_vector_type(8)));
typedef float f32x4 __attribute__((ext_vector_type(4)));
typedef unsigned short u16;

__device__ inline float b2f(u16 h) {
    unsigned int u = ((unsigned int)h) << 16;
    float f;
    __builtin_memcpy(&f, &u, 4);
    return f;
}

__device__ inline u16 f2b(float f) {
    unsigned int u;
    __builtin_memcpy(&u, &f, 4);
    unsigned int lsb = (u >> 16) & 1u;
    u += 0x7fffu + lsb;
    return (u16)(u >> 16);
}

// async 16B global -> LDS (wave-uniform base + lane*16 at all call sites)
__device__ __forceinline__ void gl2lds16(const u16* g, u16* l) {
    __builtin_amdgcn_global_load_lds(
        (const __attribute__((address_space(1))) unsigned int*)g,
        (__attribute__((address_space(3))) unsigned int*)l,
        16, 0, 0);
}

#define PITCH 72   // wtrans scratch pitch

// log2(e) / 8  (softmax temperature sqrt(64)=8 folded into Q projection)
#define QSCALE 0.18033688011112042f

// ---------------------------------------------------------------------------
// Prep A: x f32 -> bf16
// ---------------------------------------------------------------------------
__global__ __launch_bounds__(256) void cvt_kernel(const float* __restrict__ x,
                                                  u16* __restrict__ xb) {
    int idx = blockIdx.x * 256 + threadIdx.x;   // 2,097,152 float4s
    float4 v = ((const float4*)x)[idx];
    ushort4 o;
    o.x = f2b(v.x); o.y = f2b(v.y); o.z = f2b(v.z); o.w = f2b(v.w);
    ((ushort4*)xb)[idx] = o;
}

// ---------------------------------------------------------------------------
// Prep B: transpose+convert four 512x512 f32 weights into bf16 WT[n][k].
// Order: q, k, v, o (k and v adjacent -> fused KV GEMM sees 1024 N-rows).
// ---------------------------------------------------------------------------
__global__ __launch_bounds__(256) void wtrans_kernel(const float* __restrict__ w0,
                                                     const float* __restrict__ w1,
                                                     const float* __restrict__ w2,
                                                     const float* __restrict__ w3,
                                                     u16* __restrict__ wt) {
    const float* W = blockIdx.z == 0 ? w0 : blockIdx.z == 1 ? w1
                   : blockIdx.z == 2 ? w2 : w3;
    u16* WT = wt + (size_t)blockIdx.z * 262144;
    __shared__ u16 T[64 * PITCH];
    int tid = threadIdx.x;
    int nB = blockIdx.x * 64, kB = blockIdx.y * 64;
#pragma unroll
    for (int t = 0; t < 4; ++t) {
        int e = tid + t * 256;
        int r = e >> 4, c4 = (e & 15) * 4;
        float4 v = *(const float4*)(&W[(size_t)(kB + r) * 512 + nB + c4]);
        u16* dst = &T[r * PITCH + c4];
        dst[0] = f2b(v.x); dst[1] = f2b(v.y); dst[2] = f2b(v.z); dst[3] = f2b(v.w);
    }
    __syncthreads();
    int n = tid & 63, kg = tid >> 6;
#pragma unroll
    for (int p = 0; p < 2; ++p) {
        int k0 = (kg + p * 4) * 8;
        u16 tmp[8];
#pragma unroll
        for (int i = 0; i < 8; ++i) tmp[i] = T[(k0 + i) * PITCH + n];
        *(int4*)(&WT[(size_t)(nB + n) * 512 + kB + k0]) = *(int4*)tmp;
    }
}

// ---------------------------------------------------------------------------
// Kernel 1: TF avg-pool 3x3/s2 SAME (divide by valid count), bf16 in/out.
// Vectorized: one thread = 8 channels (b128 loads/stores).
// ---------------------------------------------------------------------------
__global__ __launch_bounds__(256) void pool_kernel(const u16* __restrict__ xb,
                                                   u16* __restrict__ xp) {
    int idx = blockIdx.x * 256 + threadIdx.x;   // 262,144 = (4,32,32,64)
    int c8 = idx & 63;
    int j = (idx >> 6) & 31;
    int i = (idx >> 11) & 31;
    int b = idx >> 16;
    int r0 = 2 * i, c0 = 2 * j;
    int rmax = min(r0 + 3, 64), cmax = min(c0 + 3, 64);
    float acc[8] = {};
    for (int r = r0; r < rmax; ++r)
        for (int cc = c0; cc < cmax; ++cc) {
            bf16x8 v = *(const bf16x8*)(
                &xb[(size_t)((((b << 6) + r) << 6) + cc) * 512 + c8 * 8]);
#pragma unroll
            for (int t = 0; t < 8; ++t) acc[t] += b2f(((const u16*)&v)[t]);
        }
    float inv = 1.f / (float)((rmax - r0) * (cmax - c0));
    u16 o[8];
#pragma unroll
    for (int t = 0; t < 8; ++t) o[t] = f2b(acc[t] * inv);
    *(int4*)(&xp[(size_t)idx * 8]) = *(int4*)o;
}

// ---------------------------------------------------------------------------
// Kernel 2: m97-class GEMM. Tile 128x128, BK=64, 4 waves 2x2; global_load_lds
// into XOR-8 swizzled LDS. OM=0: bf16 row-major * oscale. OM=1: f32 + f32
// residual. OM=3: fused K|V (N=1024): cols<512 -> Kw row-major, cols>=512 ->
// V^T per-group layout into Cv2.
// ---------------------------------------------------------------------------
template <int OM>
__global__ __launch_bounds__(256, 2) void gemm_bf16(const u16* __restrict__ A,
                                                    const u16* __restrict__ WT,
                                                    const float* __restrict__ bias,
                                                    const float* __restrict__ bias2res,
                                                    void* __restrict__ Cv,
                                                    void* __restrict__ Cv2,
                                                    float oscale) {
    __shared__ __align__(16) u16 At[128 * 64];
    __shared__ __align__(16) u16 Bt[128 * 64];
    int tid = threadIdx.x, lane = tid & 63, wave = tid >> 6;
    int q = lane >> 4, l16 = lane & 15;
    int wm = wave & 1, wn = wave >> 1;
    int nBase = blockIdx.x * 128, mBase = blockIdx.y * 128;
    f32x4 acc[4][4] = {};

    for (int kk = 0; kk < 512; kk += 64) {
        __syncthreads();
#pragma unroll
        for (int t = 0; t < 4; ++t) {
            int c = wave * 64 + lane + t * 256;       // chunk slot 0..1023
            int m = c >> 3, kc = (c & 7) ^ (m & 7);   // source chunk for slot
            gl2lds16(&A[(size_t)(mBase + m) * 512 + kk + kc * 8], &At[c * 8]);
            gl2lds16(&WT[(size_t)(nBase + m) * 512 + kk + kc * 8], &Bt[c * 8]);
        }
        __syncthreads();
#pragma unroll
        for (int ds = 0; ds < 2; ++ds) {
            bf16x8 a[4], b[4];
#pragma unroll
            for (int i = 0; i < 4; ++i) {
                int ma = wm * 64 + i * 16 + l16;
                a[i] = *(bf16x8*)(&At[ma * 64 + ((((ds << 2) + q) ^ (ma & 7)) << 3)]);
                int nb = wn * 64 + i * 16 + l16;
                b[i] = *(bf16x8*)(&Bt[nb * 64 + ((((ds << 2) + q) ^ (nb & 7)) << 3)]);
            }
#pragma unroll
            for (int i = 0; i < 4; ++i)
#pragma unroll
                for (int j = 0; j < 4; ++j)
                    acc[i][j] = __builtin_amdgcn_mfma_f32_16x16x32_bf16(a[i], b[j], acc[i][j], 0, 0, 0);
        }
    }

    bool isK = (OM != 3) || (nBase < 512);
#pragma unroll
    for (int j = 0; j < 4; ++j) {
        int col = nBase + wn * 64 + j * 16 + l16;
        float bv;
        if constexpr (OM == 3) bv = isK ? bias[col] : bias2res[col - 512];
        else bv = bias[col];
#pragma unroll
        for (int i = 0; i < 4; ++i) {
#pragma unroll
            for (int r = 0; r < 4; ++r) {
                int row = mBase + wm * 64 + i * 16 + q * 4 + r;
                float v = acc[i][j][r] + bv;
                if constexpr (OM == 1) {
                    v += bias2res[(size_t)row * 512 + col];
                    ((float*)Cv)[(size_t)row * 512 + col] = v;
                } else if constexpr (OM == 0) {
                    ((u16*)Cv)[(size_t)row * 512 + col] = f2b(v * oscale);
                } else {
                    if (isK) {
                        ((u16*)Cv)[(size_t)row * 512 + col] = f2b(v);
                    } else {
                        int colv = col - 512;
                        int g = row >> 7, m2 = ((row & 127) << 3) + (colv >> 6), d = colv & 63;
                        ((u16*)Cv2)[(size_t)((g << 6) + d) * 1024 + m2] = f2b(v);
                    }
                }
            }
        }
    }
}

// ---------------------------------------------------------------------------
// Kernel 3: flash attention per group, S^T formulation.
// Structure = round-0 harness-verified version (single-buffer 128-m tiles,
// 2 barriers/iter, no hoisted staging pointers -> no scratch spill; round-2's
// double-buffer pipelining spilled: WRITE_SIZE 16->183 MB, attn 70->80 µs).
// VALU cut kept from round 1 (the part that worked; VALUBusy 54->23):
//   - exp2 via raw v_exp_f32 builtin (no denormal fixup; |z| < 50)
//   - P->bf16 packing via v_cvt_pk_bf16_f32 (2 instrs vs 6, RNE rounding)
// kf fragments stay transient (8 VGPRs); VGPR budget 128/wave at occ 4.
// LDS = 40960 B -> exactly 4 blocks/CU; grid 1024.
// ---------------------------------------------------------------------------
__global__ __launch_bounds__(256, 4) void attn_kernel(const u16* __restrict__ Q,
                                                      const u16* __restrict__ K,
                                                      const u16* __restrict__ VT_g,
                                                      u16* __restrict__ O) {
    int g = blockIdx.y;
    int qtile = blockIdx.x;   // 0..31
    const u16* Qg = Q + (size_t)g * 262144;
    const u16* Kg = K + (size_t)g * 65536;
    const u16* Vt = VT_g + (size_t)g * 65536;   // [d][m], pitch 1024
    u16* Og = O + (size_t)g * 262144;

    __shared__ __align__(16) u16 Kt[128 * 64];    // XOR-8 swizzled [m][d]
    __shared__ __align__(16) u16 VTs[64 * 128];   // XOR-16 swizzled [d][m]
    __shared__ __align__(16) u16 Pt[64 * 64];     // XOR-4dw swizzled [n][m-half]

    int tid = threadIdx.x, lane = tid & 63, wave = tid >> 6;
    int q = lane >> 4, l16 = lane & 15;
    int n0 = qtile * 128;
    int pkey = (l16 & 7) << 2;            // dword-XOR key for Pt
    int prow = (wave * 16 + l16) * 32;    // Pt row base (dwords)
    int* Pt32 = (int*)Pt;

    bf16x8 qf[2][2];
#pragma unroll
    for (int s = 0; s < 2; ++s)
#pragma unroll
        for (int ds = 0; ds < 2; ++ds)
            qf[s][ds] = *(const bf16x8*)(
                &Qg[(size_t)(n0 + s * 64 + wave * 16 + l16) * 64 + ds * 32 + q * 8]);

    f32x4 oacc[2][4] = {};
    float rsum[2] = {0.f, 0.f};

    for (int kb = 0; kb < 8; ++kb) {
        __syncthreads();
#pragma unroll
        for (int t = 0; t < 4; ++t) {
            int c = wave * 64 + lane + t * 256;       // slot 0..1023
            {   // K tile: 128 m-rows x 64 d, XOR-8
                int m = c >> 3, kc = (c & 7) ^ (m & 7);
                gl2lds16(&Kg[(size_t)(kb * 128 + m) * 64 + kc * 8], &Kt[c * 8]);
            }
            {   // V^T tile: 64 d-rows x 128 m, XOR-16
                int d = c >> 4, mc = (c & 15) ^ (d & 15);
                gl2lds16(&Vt[(size_t)d * 1024 + kb * 128 + mc * 8], &VTs[c * 8]);
            }
        }
        __syncthreads();

#pragma unroll
        for (int h = 0; h < 2; ++h) {
#pragma unroll
            for (int s = 0; s < 2; ++s) {
                // S^T block; p = exp2(z); packed b64 write to Pt[n][m]
#pragma unroll
                for (int cb = 0; cb < 4; ++cb) {
                    int m = h * 64 + cb * 16 + l16;
                    bf16x8 kf0 = *(bf16x8*)(&Kt[m * 64 + ((q ^ (m & 7)) << 3)]);
                    bf16x8 kf1 = *(bf16x8*)(&Kt[m * 64 + (((4 + q) ^ (m & 7)) << 3)]);
                    f32x4 z = {};
                    z = __builtin_amdgcn_mfma_f32_16x16x32_bf16(kf0, qf[s][0], z, 0, 0, 0);
                    z = __builtin_amdgcn_mfma_f32_16x16x32_bf16(kf1, qf[s][1], z, 0, 0, 0);
                    float p0 = __builtin_amdgcn_exp2f(z[0]);
                    float p1 = __builtin_amdgcn_exp2f(z[1]);
                    float p2 = __builtin_amdgcn_exp2f(z[2]);
                    float p3 = __builtin_amdgcn_exp2f(z[3]);
                    rsum[s] += (p0 + p1) + (p2 + p3);
                    unsigned w0, w1;
                    asm("v_cvt_pk_bf16_f32 %0, %1, %2" : "=v"(w0) : "v"(p0), "v"(p1));
                    asm("v_cvt_pk_bf16_f32 %0, %1, %2" : "=v"(w1) : "v"(p2), "v"(p3));
                    int2 w;
                    w.x = (int)w0;
                    w.y = (int)w1;
                    int pd = (cb * 8 + q * 2) ^ pkey;
                    *(int2*)(&Pt32[prow + pd]) = w;
                }
                // O += P V (same wave wrote Pt rows; DS in-order, no barrier)
#pragma unroll
                for (int ds = 0; ds < 2; ++ds) {
                    int pd = (ds * 16 + q * 4) ^ pkey;
                    bf16x8 ap = *(bf16x8*)(&Pt32[prow + pd]);
#pragma unroll
                    for (int db = 0; db < 4; ++db) {
                        int dd = db * 16 + l16;
                        int jj = h * 8 + ds * 4 + q;
                        bf16x8 vb = *(bf16x8*)(&VTs[dd * 128 + ((jj ^ (dd & 15)) << 3)]);
                        oacc[s][db] = __builtin_amdgcn_mfma_f32_16x16x32_bf16(ap, vb, oacc[s][db], 0, 0, 0);
                    }
                }
            }
        }
    }

    // epilogue: rsum lives at row n=l16 (partial over quads) -> reduce over
    // quads, then fetch row (q*4+r)'s total via shfl, normalize, store.
#pragma unroll
    for (int s = 0; s < 2; ++s) {
        float v = rsum[s];
        v += __shfl_xor(v, 16, 64);
        v += __shfl_xor(v, 32, 64);
        rsum[s] = v;
    }
    float inv[2][4];
#pragma unroll
    for (int s = 0; s < 2; ++s)
#pragma unroll
        for (int r = 0; r < 4; ++r)
            inv[s][r] = 1.f / __shfl(rsum[s], q * 4 + r, 64);
#pragma unroll
    for (int s = 0; s < 2; ++s)
#pragma unroll
        for (int db = 0; db < 4; ++db)
#pragma unroll
            for (int r = 0; r < 4; ++r) {
                int row = n0 + s * 64 + wave * 16 + q * 4 + r;
                Og[(size_t)row * 64 + db * 16 + l16] = f2b(oacc[s][db][r] * inv[s][r]);
            }
}

// ---------------------------------------------------------------------------
extern "C" void kernel_launch(void* const* d_in, const int* in_sizes, int n_in,
                              void* d_out, int out_size, void* d_ws, size_t ws_size,
                              hipStream_t stream) {
    const float* x   = (const float*)d_in[0];
    const float* w_q = (const float*)d_in[1];
    const float* b_q = (const float*)d_in[2];
    const float* w_k = (const float*)d_in[3];
    const float* b_k = (const float*)d_in[4];
    const float* w_v = (const float*)d_in[5];
    const float* b_v = (const float*)d_in[6];
    const float* w_o = (const float*)d_in[7];
    const float* b_o = (const float*)d_in[8];
    float* out = (float*)d_out;

    char* ws = (char*)d_ws;
    u16* xb  = (u16*)(ws);                        // 16 MB (16384,512) bf16
    u16* xp  = (u16*)(ws + (16ull << 20));        //  4 MB (4096,512)
    u16* Qw  = (u16*)(ws + (20ull << 20));        // 16 MB (16384,512)
    u16* Kw  = (u16*)(ws + (36ull << 20));        //  4 MB (4096,512)
    u16* VwT = (u16*)(ws + (40ull << 20));        //  4 MB 32x(64,1024)
    u16* wT  = (u16*)(ws + (44ull << 20));        //  2 MB: 4 x 512x512 bf16
    u16* Ow  = xb;  // alias: xb's last reader (Q-GEMM) precedes attn's write

    cvt_kernel<<<8192, 256, 0, stream>>>(x, xb);
    wtrans_kernel<<<dim3(8, 8, 4), 256, 0, stream>>>(w_q, w_k, w_v, w_o, wT);
    pool_kernel<<<1024, 256, 0, stream>>>(xb, xp);
    // Q projection (scaled by log2(e)/8)
    gemm_bf16<0><<<dim3(4, 128), 256, 0, stream>>>(xb, wT, b_q, nullptr, Qw, nullptr, QSCALE);
    // fused K|V projection (N=1024 over adjacent K^T,V^T weights)
    gemm_bf16<3><<<dim3(8, 32), 256, 0, stream>>>(xp, wT + 262144, b_k, b_v, Kw, VwT, 1.0f);
    // attention: 32 q-tiles x 32 groups
    attn_kernel<<<dim3(32, 32), 256, 0, stream>>>(Qw, Kw, VwT, Ow);
    // output projection + f32 residual
    gemm_bf16<1><<<dim3(4, 128), 256, 0, stream>>>(Ow, wT + 786432, b_o, x, out, nullptr, 1.0f);
}

// Round 4
// 213.849 us; speedup vs baseline: 1.1665x; 1.0502x over previous
//
#include <hip/hip_runtime.h>
#include <hip/hip_bf16.h>
#include <math.h>

typedef short bf16x8 __attribute__((ext_vector_type(8)));
typedef float f32x4 __attribute__((ext_vector_type(4)));
typedef unsigned short u16;

__device__ inline float b2f(u16 h) {
    unsigned int u = ((unsigned int)h) << 16;
    float f;
    __builtin_memcpy(&f, &u, 4);
    return f;
}

__device__ inline u16 f2b(float f) {
    unsigned int u;
    __builtin_memcpy(&u, &f, 4);
    unsigned int lsb = (u >> 16) & 1u;
    u += 0x7fffu + lsb;
    return (u16)(u >> 16);
}

// async 16B global -> LDS (wave-uniform base + lane*16 at all call sites)
__device__ __forceinline__ void gl2lds16(const u16* g, u16* l) {
    __builtin_amdgcn_global_load_lds(
        (const __attribute__((address_space(1))) unsigned int*)g,
        (__attribute__((address_space(3))) unsigned int*)l,
        16, 0, 0);
}

#define PITCH 72   // wtrans scratch pitch

// log2(e) / 8  (softmax temperature sqrt(64)=8 folded into Q projection)
#define QSCALE 0.18033688011112042f

// ---------------------------------------------------------------------------
// Prep A: x f32 -> bf16
// ---------------------------------------------------------------------------
__global__ __launch_bounds__(256) void cvt_kernel(const float* __restrict__ x,
                                                  u16* __restrict__ xb) {
    int idx = blockIdx.x * 256 + threadIdx.x;   // 2,097,152 float4s
    float4 v = ((const float4*)x)[idx];
    ushort4 o;
    o.x = f2b(v.x); o.y = f2b(v.y); o.z = f2b(v.z); o.w = f2b(v.w);
    ((ushort4*)xb)[idx] = o;
}

// ---------------------------------------------------------------------------
// Prep B: transpose+convert four 512x512 f32 weights into bf16 WT[n][k].
// Order: q, k, v, o (k and v adjacent -> fused KV GEMM sees 1024 N-rows).
// ---------------------------------------------------------------------------
__global__ __launch_bounds__(256) void wtrans_kernel(const float* __restrict__ w0,
                                                     const float* __restrict__ w1,
                                                     const float* __restrict__ w2,
                                                     const float* __restrict__ w3,
                                                     u16* __restrict__ wt) {
    const float* W = blockIdx.z == 0 ? w0 : blockIdx.z == 1 ? w1
                   : blockIdx.z == 2 ? w2 : w3;
    u16* WT = wt + (size_t)blockIdx.z * 262144;
    __shared__ u16 T[64 * PITCH];
    int tid = threadIdx.x;
    int nB = blockIdx.x * 64, kB = blockIdx.y * 64;
#pragma unroll
    for (int t = 0; t < 4; ++t) {
        int e = tid + t * 256;
        int r = e >> 4, c4 = (e & 15) * 4;
        float4 v = *(const float4*)(&W[(size_t)(kB + r) * 512 + nB + c4]);
        u16* dst = &T[r * PITCH + c4];
        dst[0] = f2b(v.x); dst[1] = f2b(v.y); dst[2] = f2b(v.z); dst[3] = f2b(v.w);
    }
    __syncthreads();
    int n = tid & 63, kg = tid >> 6;
#pragma unroll
    for (int p = 0; p < 2; ++p) {
        int k0 = (kg + p * 4) * 8;
        u16 tmp[8];
#pragma unroll
        for (int i = 0; i < 8; ++i) tmp[i] = T[(k0 + i) * PITCH + n];
        *(int4*)(&WT[(size_t)(nB + n) * 512 + kB + k0]) = *(int4*)tmp;
    }
}

// ---------------------------------------------------------------------------
// Kernel 1: TF avg-pool 3x3/s2 SAME (divide by valid count), bf16 in/out.
// Vectorized: one thread = 8 channels (b128 loads/stores).
// ---------------------------------------------------------------------------
__global__ __launch_bounds__(256) void pool_kernel(const u16* __restrict__ xb,
                                                   u16* __restrict__ xp) {
    int idx = blockIdx.x * 256 + threadIdx.x;   // 262,144 = (4,32,32,64)
    int c8 = idx & 63;
    int j = (idx >> 6) & 31;
    int i = (idx >> 11) & 31;
    int b = idx >> 16;
    int r0 = 2 * i, c0 = 2 * j;
    int rmax = min(r0 + 3, 64), cmax = min(c0 + 3, 64);
    float acc[8] = {};
    for (int r = r0; r < rmax; ++r)
        for (int cc = c0; cc < cmax; ++cc) {
            bf16x8 v = *(const bf16x8*)(
                &xb[(size_t)((((b << 6) + r) << 6) + cc) * 512 + c8 * 8]);
#pragma unroll
            for (int t = 0; t < 8; ++t) acc[t] += b2f(((const u16*)&v)[t]);
        }
    float inv = 1.f / (float)((rmax - r0) * (cmax - c0));
    u16 o[8];
#pragma unroll
    for (int t = 0; t < 8; ++t) o[t] = f2b(acc[t] * inv);
    *(int4*)(&xp[(size_t)idx * 8]) = *(int4*)o;
}

// ---------------------------------------------------------------------------
// Kernel 2: m97-class GEMM. Tile 128x128, BK=64, 4 waves 2x2; global_load_lds
// into XOR-8 swizzled LDS. OM=0: bf16 row-major * oscale. OM=1: f32 + f32
// residual. OM=3: fused K|V (N=1024): cols<512 -> Kw row-major, cols>=512 ->
// V^T per-group layout into Cv2.
// XCD remap: blocks sharing an A row-panel (same mBlk, all nBlk) are made to
// differ by gridDim.y (multiple of 8) in linear id -> same XCD L2 holds the
// panel for all its consumers (default consecutive-id layout scattered them
// across all 8 XCDs, forcing cross-XCD/L3 re-fetch of A).
// ---------------------------------------------------------------------------
template <int OM>
__global__ __launch_bounds__(256, 2) void gemm_bf16(const u16* __restrict__ A,
                                                    const u16* __restrict__ WT,
                                                    const float* __restrict__ bias,
                                                    const float* __restrict__ bias2res,
                                                    void* __restrict__ Cv,
                                                    void* __restrict__ Cv2,
                                                    float oscale) {
    __shared__ __align__(16) u16 At[128 * 64];
    __shared__ __align__(16) u16 Bt[128 * 64];
    int tid = threadIdx.x, lane = tid & 63, wave = tid >> 6;
    int q = lane >> 4, l16 = lane & 15;
    int wm = wave & 1, wn = wave >> 1;
    int bid = blockIdx.y * gridDim.x + blockIdx.x;
    int nBlk = bid / gridDim.y;          // A-panel sharers: bid ± k*gridDim.y
    int mBlk = bid - nBlk * gridDim.y;   // gridDim.y % 8 == 0 -> same XCD
    int nBase = nBlk * 128, mBase = mBlk * 128;
    f32x4 acc[4][4] = {};

    for (int kk = 0; kk < 512; kk += 64) {
        __syncthreads();
#pragma unroll
        for (int t = 0; t < 4; ++t) {
            int c = wave * 64 + lane + t * 256;       // chunk slot 0..1023
            int m = c >> 3, kc = (c & 7) ^ (m & 7);   // source chunk for slot
            gl2lds16(&A[(size_t)(mBase + m) * 512 + kk + kc * 8], &At[c * 8]);
            gl2lds16(&WT[(size_t)(nBase + m) * 512 + kk + kc * 8], &Bt[c * 8]);
        }
        __syncthreads();
#pragma unroll
        for (int ds = 0; ds < 2; ++ds) {
            bf16x8 a[4], b[4];
#pragma unroll
            for (int i = 0; i < 4; ++i) {
                int ma = wm * 64 + i * 16 + l16;
                a[i] = *(bf16x8*)(&At[ma * 64 + ((((ds << 2) + q) ^ (ma & 7)) << 3)]);
                int nb = wn * 64 + i * 16 + l16;
                b[i] = *(bf16x8*)(&Bt[nb * 64 + ((((ds << 2) + q) ^ (nb & 7)) << 3)]);
            }
#pragma unroll
            for (int i = 0; i < 4; ++i)
#pragma unroll
                for (int j = 0; j < 4; ++j)
                    acc[i][j] = __builtin_amdgcn_mfma_f32_16x16x32_bf16(a[i], b[j], acc[i][j], 0, 0, 0);
        }
    }

    bool isK = (OM != 3) || (nBase < 512);
#pragma unroll
    for (int j = 0; j < 4; ++j) {
        int col = nBase + wn * 64 + j * 16 + l16;
        float bv;
        if constexpr (OM == 3) bv = isK ? bias[col] : bias2res[col - 512];
        else bv = bias[col];
#pragma unroll
        for (int i = 0; i < 4; ++i) {
#pragma unroll
            for (int r = 0; r < 4; ++r) {
                int row = mBase + wm * 64 + i * 16 + q * 4 + r;
                float v = acc[i][j][r] + bv;
                if constexpr (OM == 1) {
                    v += bias2res[(size_t)row * 512 + col];
                    ((float*)Cv)[(size_t)row * 512 + col] = v;
                } else if constexpr (OM == 0) {
                    ((u16*)Cv)[(size_t)row * 512 + col] = f2b(v * oscale);
                } else {
                    if (isK) {
                        ((u16*)Cv)[(size_t)row * 512 + col] = f2b(v);
                    } else {
                        int colv = col - 512;
                        int g = row >> 7, m2 = ((row & 127) << 3) + (colv >> 6), d = colv & 63;
                        ((u16*)Cv2)[(size_t)((g << 6) + d) * 1024 + m2] = f2b(v);
                    }
                }
            }
        }
    }
}

// ---------------------------------------------------------------------------
// Kernel 3: flash attention per group, S^T formulation.
// Structure = harness-verified single-buffer version (round-2 double-buffer
// spilled scratch: WRITE 16->183 MB). VALU cut kept (exp2 builtin + cvt_pk).
// XCD locality (this round): g = blockIdx.x, qtile = blockIdx.y -> linear id
// = qtile*32 + g -> XCD = g & 7. All 32 q-tile blocks of group g share one
// XCD's L2 for its 128 KB K/V (per-XCD working set: 4 groups = 512 KB K/V +
// 2 MB Q, L2-resident; was: every XCD caching all 32 groups = 4 MB + Q
// streaming through -> K/V re-reads from L3/HBM, exposed in the per-iter
// vmcnt(0) drain).
// LDS = 40960 B -> exactly 4 blocks/CU; grid 1024.
// ---------------------------------------------------------------------------
__global__ __launch_bounds__(256, 4) void attn_kernel(const u16* __restrict__ Q,
                                                      const u16* __restrict__ K,
                                                      const u16* __restrict__ VT_g,
                                                      u16* __restrict__ O) {
    int g = blockIdx.x;       // XCD = g & 7 (round-robin by linear id)
    int qtile = blockIdx.y;   // 0..31
    const u16* Qg = Q + (size_t)g * 262144;
    const u16* Kg = K + (size_t)g * 65536;
    const u16* Vt = VT_g + (size_t)g * 65536;   // [d][m], pitch 1024
    u16* Og = O + (size_t)g * 262144;

    __shared__ __align__(16) u16 Kt[128 * 64];    // XOR-8 swizzled [m][d]
    __shared__ __align__(16) u16 VTs[64 * 128];   // XOR-16 swizzled [d][m]
    __shared__ __align__(16) u16 Pt[64 * 64];     // XOR-4dw swizzled [n][m-half]

    int tid = threadIdx.x, lane = tid & 63, wave = tid >> 6;
    int q = lane >> 4, l16 = lane & 15;
    int n0 = qtile * 128;
    int pkey = (l16 & 7) << 2;            // dword-XOR key for Pt
    int prow = (wave * 16 + l16) * 32;    // Pt row base (dwords)
    int* Pt32 = (int*)Pt;

    bf16x8 qf[2][2];
#pragma unroll
    for (int s = 0; s < 2; ++s)
#pragma unroll
        for (int ds = 0; ds < 2; ++ds)
            qf[s][ds] = *(const bf16x8*)(
                &Qg[(size_t)(n0 + s * 64 + wave * 16 + l16) * 64 + ds * 32 + q * 8]);

    f32x4 oacc[2][4] = {};
    float rsum[2] = {0.f, 0.f};

    for (int kb = 0; kb < 8; ++kb) {
        __syncthreads();
#pragma unroll
        for (int t = 0; t < 4; ++t) {
            int c = wave * 64 + lane + t * 256;       // slot 0..1023
            {   // K tile: 128 m-rows x 64 d, XOR-8
                int m = c >> 3, kc = (c & 7) ^ (m & 7);
                gl2lds16(&Kg[(size_t)(kb * 128 + m) * 64 + kc * 8], &Kt[c * 8]);
            }
            {   // V^T tile: 64 d-rows x 128 m, XOR-16
                int d = c >> 4, mc = (c & 15) ^ (d & 15);
                gl2lds16(&Vt[(size_t)d * 1024 + kb * 128 + mc * 8], &VTs[c * 8]);
            }
        }
        __syncthreads();

#pragma unroll
        for (int h = 0; h < 2; ++h) {
#pragma unroll
            for (int s = 0; s < 2; ++s) {
                // S^T block; p = exp2(z); packed b64 write to Pt[n][m]
#pragma unroll
                for (int cb = 0; cb < 4; ++cb) {
                    int m = h * 64 + cb * 16 + l16;
                    bf16x8 kf0 = *(bf16x8*)(&Kt[m * 64 + ((q ^ (m & 7)) << 3)]);
                    bf16x8 kf1 = *(bf16x8*)(&Kt[m * 64 + (((4 + q) ^ (m & 7)) << 3)]);
                    f32x4 z = {};
                    z = __builtin_amdgcn_mfma_f32_16x16x32_bf16(kf0, qf[s][0], z, 0, 0, 0);
                    z = __builtin_amdgcn_mfma_f32_16x16x32_bf16(kf1, qf[s][1], z, 0, 0, 0);
                    float p0 = __builtin_amdgcn_exp2f(z[0]);
                    float p1 = __builtin_amdgcn_exp2f(z[1]);
                    float p2 = __builtin_amdgcn_exp2f(z[2]);
                    float p3 = __builtin_amdgcn_exp2f(z[3]);
                    rsum[s] += (p0 + p1) + (p2 + p3);
                    unsigned w0, w1;
                    asm("v_cvt_pk_bf16_f32 %0, %1, %2" : "=v"(w0) : "v"(p0), "v"(p1));
                    asm("v_cvt_pk_bf16_f32 %0, %1, %2" : "=v"(w1) : "v"(p2), "v"(p3));
                    int2 w;
                    w.x = (int)w0;
                    w.y = (int)w1;
                    int pd = (cb * 8 + q * 2) ^ pkey;
                    *(int2*)(&Pt32[prow + pd]) = w;
                }
                // O += P V (same wave wrote Pt rows; DS in-order, no barrier)
#pragma unroll
                for (int ds = 0; ds < 2; ++ds) {
                    int pd = (ds * 16 + q * 4) ^ pkey;
                    bf16x8 ap = *(bf16x8*)(&Pt32[prow + pd]);
#pragma unroll
                    for (int db = 0; db < 4; ++db) {
                        int dd = db * 16 + l16;
                        int jj = h * 8 + ds * 4 + q;
                        bf16x8 vb = *(bf16x8*)(&VTs[dd * 128 + ((jj ^ (dd & 15)) << 3)]);
                        oacc[s][db] = __builtin_amdgcn_mfma_f32_16x16x32_bf16(ap, vb, oacc[s][db], 0, 0, 0);
                    }
                }
            }
        }
    }

    // epilogue: rsum lives at row n=l16 (partial over quads) -> reduce over
    // quads, then fetch row (q*4+r)'s total via shfl, normalize, store.
#pragma unroll
    for (int s = 0; s < 2; ++s) {
        float v = rsum[s];
        v += __shfl_xor(v, 16, 64);
        v += __shfl_xor(v, 32, 64);
        rsum[s] = v;
    }
    float inv[2][4];
#pragma unroll
    for (int s = 0; s < 2; ++s)
#pragma unroll
        for (int r = 0; r < 4; ++r)
            inv[s][r] = 1.f / __shfl(rsum[s], q * 4 + r, 64);
#pragma unroll
    for (int s = 0; s < 2; ++s)
#pragma unroll
        for (int db = 0; db < 4; ++db)
#pragma unroll
            for (int r = 0; r < 4; ++r) {
                int row = n0 + s * 64 + wave * 16 + q * 4 + r;
                Og[(size_t)row * 64 + db * 16 + l16] = f2b(oacc[s][db][r] * inv[s][r]);
            }
}

// ---------------------------------------------------------------------------
extern "C" void kernel_launch(void* const* d_in, const int* in_sizes, int n_in,
                              void* d_out, int out_size, void* d_ws, size_t ws_size,
                              hipStream_t stream) {
    const float* x   = (const float*)d_in[0];
    const float* w_q = (const float*)d_in[1];
    const float* b_q = (const float*)d_in[2];
    const float* w_k = (const float*)d_in[3];
    const float* b_k = (const float*)d_in[4];
    const float* w_v = (const float*)d_in[5];
    const float* b_v = (const float*)d_in[6];
    const float* w_o = (const float*)d_in[7];
    const float* b_o = (const float*)d_in[8];
    float* out = (float*)d_out;

    char* ws = (char*)d_ws;
    u16* xb  = (u16*)(ws);                        // 16 MB (16384,512) bf16
    u16* xp  = (u16*)(ws + (16ull << 20));        //  4 MB (4096,512)
    u16* Qw  = (u16*)(ws + (20ull << 20));        // 16 MB (16384,512)
    u16* Kw  = (u16*)(ws + (36ull << 20));        //  4 MB (4096,512)
    u16* VwT = (u16*)(ws + (40ull << 20));        //  4 MB 32x(64,1024)
    u16* wT  = (u16*)(ws + (44ull << 20));        //  2 MB: 4 x 512x512 bf16
    u16* Ow  = xb;  // alias: xb's last reader (Q-GEMM) precedes attn's write

    cvt_kernel<<<8192, 256, 0, stream>>>(x, xb);
    wtrans_kernel<<<dim3(8, 8, 4), 256, 0, stream>>>(w_q, w_k, w_v, w_o, wT);
    pool_kernel<<<1024, 256, 0, stream>>>(xb, xp);
    // Q projection (scaled by log2(e)/8)
    gemm_bf16<0><<<dim3(4, 128), 256, 0, stream>>>(xb, wT, b_q, nullptr, Qw, nullptr, QSCALE);
    // fused K|V projection (N=1024 over adjacent K^T,V^T weights)
    gemm_bf16<3><<<dim3(8, 32), 256, 0, stream>>>(xp, wT + 262144, b_k, b_v, Kw, VwT, 1.0f);
    // attention: 32 groups (x: XCD-pinned) x 32 q-tiles (y)
    attn_kernel<<<dim3(32, 32), 256, 0, stream>>>(Qw, Kw, VwT, Ow);
    // output projection + f32 residual
    gemm_bf16<1><<<dim3(4, 128), 256, 0, stream>>>(Ow, wT + 786432, b_o, x, out, nullptr, 1.0f);
}

// Round 5
// 200.489 us; speedup vs baseline: 1.2442x; 1.0666x over previous
//
#include <hip/hip_runtime.h>
#include <hip/hip_bf16.h>
#include <math.h>

typedef short bf16x8 __attribute__((ext_vector_type(8)));
typedef float f32x4 __attribute__((ext_vector_type(4)));
typedef unsigned short u16;

__device__ inline float b2f(u16 h) {
    unsigned int u = ((unsigned int)h) << 16;
    float f;
    __builtin_memcpy(&f, &u, 4);
    return f;
}

__device__ inline u16 f2b(float f) {
    unsigned int u;
    __builtin_memcpy(&u, &f, 4);
    unsigned int lsb = (u >> 16) & 1u;
    u += 0x7fffu + lsb;
    return (u16)(u >> 16);
}

// async 16B global -> LDS (wave-uniform base + lane*16 at all call sites)
__device__ __forceinline__ void gl2lds16(const u16* g, u16* l) {
    __builtin_amdgcn_global_load_lds(
        (const __attribute__((address_space(1))) unsigned int*)g,
        (__attribute__((address_space(3))) unsigned int*)l,
        16, 0, 0);
}

#define PITCH 72   // wtrans scratch pitch

// log2(e) / 8  (softmax temperature sqrt(64)=8 folded into Q projection)
#define QSCALE 0.18033688011112042f

// ---------------------------------------------------------------------------
// Prep A: x f32 -> bf16
// ---------------------------------------------------------------------------
__global__ __launch_bounds__(256) void cvt_kernel(const float* __restrict__ x,
                                                  u16* __restrict__ xb) {
    int idx = blockIdx.x * 256 + threadIdx.x;   // 2,097,152 float4s
    float4 v = ((const float4*)x)[idx];
    ushort4 o;
    o.x = f2b(v.x); o.y = f2b(v.y); o.z = f2b(v.z); o.w = f2b(v.w);
    ((ushort4*)xb)[idx] = o;
}

// ---------------------------------------------------------------------------
// Prep B: transpose+convert four 512x512 f32 weights into bf16 WT[n][k].
// Order: q, k, v, o (k and v adjacent -> fused KV GEMM sees 1024 N-rows).
// ---------------------------------------------------------------------------
__global__ __launch_bounds__(256) void wtrans_kernel(const float* __restrict__ w0,
                                                     const float* __restrict__ w1,
                                                     const float* __restrict__ w2,
                                                     const float* __restrict__ w3,
                                                     u16* __restrict__ wt) {
    const float* W = blockIdx.z == 0 ? w0 : blockIdx.z == 1 ? w1
                   : blockIdx.z == 2 ? w2 : w3;
    u16* WT = wt + (size_t)blockIdx.z * 262144;
    __shared__ u16 T[64 * PITCH];
    int tid = threadIdx.x;
    int nB = blockIdx.x * 64, kB = blockIdx.y * 64;
#pragma unroll
    for (int t = 0; t < 4; ++t) {
        int e = tid + t * 256;
        int r = e >> 4, c4 = (e & 15) * 4;
        float4 v = *(const float4*)(&W[(size_t)(kB + r) * 512 + nB + c4]);
        u16* dst = &T[r * PITCH + c4];
        dst[0] = f2b(v.x); dst[1] = f2b(v.y); dst[2] = f2b(v.z); dst[3] = f2b(v.w);
    }
    __syncthreads();
    int n = tid & 63, kg = tid >> 6;
#pragma unroll
    for (int p = 0; p < 2; ++p) {
        int k0 = (kg + p * 4) * 8;
        u16 tmp[8];
#pragma unroll
        for (int i = 0; i < 8; ++i) tmp[i] = T[(k0 + i) * PITCH + n];
        *(int4*)(&WT[(size_t)(nB + n) * 512 + kB + k0]) = *(int4*)tmp;
    }
}

// ---------------------------------------------------------------------------
// Kernel 1: TF avg-pool 3x3/s2 SAME (divide by valid count), bf16 in/out.
// Vectorized: one thread = 8 channels (b128 loads/stores).
// ---------------------------------------------------------------------------
__global__ __launch_bounds__(256) void pool_kernel(const u16* __restrict__ xb,
                                                   u16* __restrict__ xp) {
    int idx = blockIdx.x * 256 + threadIdx.x;   // 262,144 = (4,32,32,64)
    int c8 = idx & 63;
    int j = (idx >> 6) & 31;
    int i = (idx >> 11) & 31;
    int b = idx >> 16;
    int r0 = 2 * i, c0 = 2 * j;
    int rmax = min(r0 + 3, 64), cmax = min(c0 + 3, 64);
    float acc[8] = {};
    for (int r = r0; r < rmax; ++r)
        for (int cc = c0; cc < cmax; ++cc) {
            bf16x8 v = *(const bf16x8*)(
                &xb[(size_t)((((b << 6) + r) << 6) + cc) * 512 + c8 * 8]);
#pragma unroll
            for (int t = 0; t < 8; ++t) acc[t] += b2f(((const u16*)&v)[t]);
        }
    float inv = 1.f / (float)((rmax - r0) * (cmax - c0));
    u16 o[8];
#pragma unroll
    for (int t = 0; t < 8; ++t) o[t] = f2b(acc[t] * inv);
    *(int4*)(&xp[(size_t)idx * 8]) = *(int4*)o;
}

// ---------------------------------------------------------------------------
// Kernel 2: GEMM, tile 64x128 (MxN), BK=64, 4 waves 2(m)x2(n), each wave
// 32x64 -> acc[2][4]. Tile shrunk from 128x128 (round 4): grids were
// 512/256 blocks = 2/1 blocks per CU -- GRID-limited occupancy left the
// per-k-iter vmcnt(0) staging drain fully exposed. 64x128 doubles the grid:
// Q/O 1024 blocks (4/CU), KV 512 (2/CU). LDS 24 KB (At 8K + Bt 16K);
// acc 32 AGPR -> fits 128 VGPR cap of __launch_bounds__(256,4).
// XCD remap kept: A-panel sharers differ by gridDim.y (mult of 8) -> same
// XCD L2 serves the panel (round-4 win: FETCH dropped, total -11 us).
// OM=0: bf16 * oscale. OM=1: f32 + residual. OM=3: fused K|V.
// ---------------------------------------------------------------------------
template <int OM>
__global__ __launch_bounds__(256, 4) void gemm_bf16(const u16* __restrict__ A,
                                                    const u16* __restrict__ WT,
                                                    const float* __restrict__ bias,
                                                    const float* __restrict__ bias2res,
                                                    void* __restrict__ Cv,
                                                    void* __restrict__ Cv2,
                                                    float oscale) {
    __shared__ __align__(16) u16 At[64 * 64];
    __shared__ __align__(16) u16 Bt[128 * 64];
    int tid = threadIdx.x, lane = tid & 63, wave = tid >> 6;
    int q = lane >> 4, l16 = lane & 15;
    int wm = wave & 1, wn = wave >> 1;
    int bid = blockIdx.y * gridDim.x + blockIdx.x;
    int nBlk = bid / gridDim.y;          // A-panel sharers: bid ± k*gridDim.y
    int mBlk = bid - nBlk * gridDim.y;   // gridDim.y % 8 == 0 -> same XCD
    int nBase = nBlk * 128, mBase = mBlk * 64;
    f32x4 acc[2][4] = {};

    for (int kk = 0; kk < 512; kk += 64) {
        __syncthreads();
#pragma unroll
        for (int t = 0; t < 2; ++t) {          // At: 512 chunk slots
            int c = tid + t * 256;
            int m = c >> 3, kc = (c & 7) ^ (m & 7);
            gl2lds16(&A[(size_t)(mBase + m) * 512 + kk + kc * 8], &At[c * 8]);
        }
#pragma unroll
        for (int t = 0; t < 4; ++t) {          // Bt: 1024 chunk slots
            int c = tid + t * 256;
            int m = c >> 3, kc = (c & 7) ^ (m & 7);
            gl2lds16(&WT[(size_t)(nBase + m) * 512 + kk + kc * 8], &Bt[c * 8]);
        }
        __syncthreads();
#pragma unroll
        for (int ds = 0; ds < 2; ++ds) {
            bf16x8 a[2], b[4];
#pragma unroll
            for (int i = 0; i < 2; ++i) {
                int ma = wm * 32 + i * 16 + l16;
                a[i] = *(bf16x8*)(&At[ma * 64 + ((((ds << 2) + q) ^ (ma & 7)) << 3)]);
            }
#pragma unroll
            for (int j = 0; j < 4; ++j) {
                int nb = wn * 64 + j * 16 + l16;
                b[j] = *(bf16x8*)(&Bt[nb * 64 + ((((ds << 2) + q) ^ (nb & 7)) << 3)]);
            }
#pragma unroll
            for (int i = 0; i < 2; ++i)
#pragma unroll
                for (int j = 0; j < 4; ++j)
                    acc[i][j] = __builtin_amdgcn_mfma_f32_16x16x32_bf16(a[i], b[j], acc[i][j], 0, 0, 0);
        }
    }

    bool isK = (OM != 3) || (nBase < 512);
#pragma unroll
    for (int j = 0; j < 4; ++j) {
        int col = nBase + wn * 64 + j * 16 + l16;
        float bv;
        if constexpr (OM == 3) bv = isK ? bias[col] : bias2res[col - 512];
        else bv = bias[col];
#pragma unroll
        for (int i = 0; i < 2; ++i) {
#pragma unroll
            for (int r = 0; r < 4; ++r) {
                int row = mBase + wm * 32 + i * 16 + q * 4 + r;
                float v = acc[i][j][r] + bv;
                if constexpr (OM == 1) {
                    v += bias2res[(size_t)row * 512 + col];
                    ((float*)Cv)[(size_t)row * 512 + col] = v;
                } else if constexpr (OM == 0) {
                    ((u16*)Cv)[(size_t)row * 512 + col] = f2b(v * oscale);
                } else {
                    if (isK) {
                        ((u16*)Cv)[(size_t)row * 512 + col] = f2b(v);
                    } else {
                        int colv = col - 512;
                        int g = row >> 7, m2 = ((row & 127) << 3) + (colv >> 6), d = colv & 63;
                        ((u16*)Cv2)[(size_t)((g << 6) + d) * 1024 + m2] = f2b(v);
                    }
                }
            }
        }
    }
}

// ---------------------------------------------------------------------------
// Kernel 3: flash attention per group, S^T formulation.
// Structure = harness-verified single-buffer version. VALU cut kept (exp2
// builtin + cvt_pk). XCD pinning kept (g = blockIdx.x -> XCD = g&7; round 4:
// FETCH 41->12 MB confirmed L2 residency; time flat -> stall is intra-kernel).
// This round: s_setprio(1) around MFMA clusters (T5; +4-7% on attn per
// learn_hip m191 -- 4 independently-phased blocks/CU give the CU scheduler
// role diversity to arbitrate).
// LDS = 40960 B -> exactly 4 blocks/CU; grid 1024.
// ---------------------------------------------------------------------------
__global__ __launch_bounds__(256, 4) void attn_kernel(const u16* __restrict__ Q,
                                                      const u16* __restrict__ K,
                                                      const u16* __restrict__ VT_g,
                                                      u16* __restrict__ O) {
    int g = blockIdx.x;       // XCD = g & 7 (round-robin by linear id)
    int qtile = blockIdx.y;   // 0..31
    const u16* Qg = Q + (size_t)g * 262144;
    const u16* Kg = K + (size_t)g * 65536;
    const u16* Vt = VT_g + (size_t)g * 65536;   // [d][m], pitch 1024
    u16* Og = O + (size_t)g * 262144;

    __shared__ __align__(16) u16 Kt[128 * 64];    // XOR-8 swizzled [m][d]
    __shared__ __align__(16) u16 VTs[64 * 128];   // XOR-16 swizzled [d][m]
    __shared__ __align__(16) u16 Pt[64 * 64];     // XOR-4dw swizzled [n][m-half]

    int tid = threadIdx.x, lane = tid & 63, wave = tid >> 6;
    int q = lane >> 4, l16 = lane & 15;
    int n0 = qtile * 128;
    int pkey = (l16 & 7) << 2;            // dword-XOR key for Pt
    int prow = (wave * 16 + l16) * 32;    // Pt row base (dwords)
    int* Pt32 = (int*)Pt;

    bf16x8 qf[2][2];
#pragma unroll
    for (int s = 0; s < 2; ++s)
#pragma unroll
        for (int ds = 0; ds < 2; ++ds)
            qf[s][ds] = *(const bf16x8*)(
                &Qg[(size_t)(n0 + s * 64 + wave * 16 + l16) * 64 + ds * 32 + q * 8]);

    f32x4 oacc[2][4] = {};
    float rsum[2] = {0.f, 0.f};

    for (int kb = 0; kb < 8; ++kb) {
        __syncthreads();
#pragma unroll
        for (int t = 0; t < 4; ++t) {
            int c = wave * 64 + lane + t * 256;       // slot 0..1023
            {   // K tile: 128 m-rows x 64 d, XOR-8
                int m = c >> 3, kc = (c & 7) ^ (m & 7);
                gl2lds16(&Kg[(size_t)(kb * 128 + m) * 64 + kc * 8], &Kt[c * 8]);
            }
            {   // V^T tile: 64 d-rows x 128 m, XOR-16
                int d = c >> 4, mc = (c & 15) ^ (d & 15);
                gl2lds16(&Vt[(size_t)d * 1024 + kb * 128 + mc * 8], &VTs[c * 8]);
            }
        }
        __syncthreads();

#pragma unroll
        for (int h = 0; h < 2; ++h) {
#pragma unroll
            for (int s = 0; s < 2; ++s) {
                // S^T block; p = exp2(z); packed b64 write to Pt[n][m]
#pragma unroll
                for (int cb = 0; cb < 4; ++cb) {
                    int m = h * 64 + cb * 16 + l16;
                    bf16x8 kf0 = *(bf16x8*)(&Kt[m * 64 + ((q ^ (m & 7)) << 3)]);
                    bf16x8 kf1 = *(bf16x8*)(&Kt[m * 64 + (((4 + q) ^ (m & 7)) << 3)]);
                    f32x4 z = {};
                    __builtin_amdgcn_s_setprio(1);
                    z = __builtin_amdgcn_mfma_f32_16x16x32_bf16(kf0, qf[s][0], z, 0, 0, 0);
                    z = __builtin_amdgcn_mfma_f32_16x16x32_bf16(kf1, qf[s][1], z, 0, 0, 0);
                    __builtin_amdgcn_s_setprio(0);
                    float p0 = __builtin_amdgcn_exp2f(z[0]);
                    float p1 = __builtin_amdgcn_exp2f(z[1]);
                    float p2 = __builtin_amdgcn_exp2f(z[2]);
                    float p3 = __builtin_amdgcn_exp2f(z[3]);
                    rsum[s] += (p0 + p1) + (p2 + p3);
                    unsigned w0, w1;
                    asm("v_cvt_pk_bf16_f32 %0, %1, %2" : "=v"(w0) : "v"(p0), "v"(p1));
                    asm("v_cvt_pk_bf16_f32 %0, %1, %2" : "=v"(w1) : "v"(p2), "v"(p3));
                    int2 w;
                    w.x = (int)w0;
                    w.y = (int)w1;
                    int pd = (cb * 8 + q * 2) ^ pkey;
                    *(int2*)(&Pt32[prow + pd]) = w;
                }
                // O += P V (same wave wrote Pt rows; DS in-order, no barrier)
#pragma unroll
                for (int ds = 0; ds < 2; ++ds) {
                    int pd = (ds * 16 + q * 4) ^ pkey;
                    bf16x8 ap = *(bf16x8*)(&Pt32[prow + pd]);
                    __builtin_amdgcn_s_setprio(1);
#pragma unroll
                    for (int db = 0; db < 4; ++db) {
                        int dd = db * 16 + l16;
                        int jj = h * 8 + ds * 4 + q;
                        bf16x8 vb = *(bf16x8*)(&VTs[dd * 128 + ((jj ^ (dd & 15)) << 3)]);
                        oacc[s][db] = __builtin_amdgcn_mfma_f32_16x16x32_bf16(ap, vb, oacc[s][db], 0, 0, 0);
                    }
                    __builtin_amdgcn_s_setprio(0);
                }
            }
        }
    }

    // epilogue: rsum lives at row n=l16 (partial over quads) -> reduce over
    // quads, then fetch row (q*4+r)'s total via shfl, normalize, store.
#pragma unroll
    for (int s = 0; s < 2; ++s) {
        float v = rsum[s];
        v += __shfl_xor(v, 16, 64);
        v += __shfl_xor(v, 32, 64);
        rsum[s] = v;
    }
    float inv[2][4];
#pragma unroll
    for (int s = 0; s < 2; ++s)
#pragma unroll
        for (int r = 0; r < 4; ++r)
            inv[s][r] = 1.f / __shfl(rsum[s], q * 4 + r, 64);
#pragma unroll
    for (int s = 0; s < 2; ++s)
#pragma unroll
        for (int db = 0; db < 4; ++db)
#pragma unroll
            for (int r = 0; r < 4; ++r) {
                int row = n0 + s * 64 + wave * 16 + q * 4 + r;
                Og[(size_t)row * 64 + db * 16 + l16] = f2b(oacc[s][db][r] * inv[s][r]);
            }
}

// ---------------------------------------------------------------------------
extern "C" void kernel_launch(void* const* d_in, const int* in_sizes, int n_in,
                              void* d_out, int out_size, void* d_ws, size_t ws_size,
                              hipStream_t stream) {
    const float* x   = (const float*)d_in[0];
    const float* w_q = (const float*)d_in[1];
    const float* b_q = (const float*)d_in[2];
    const float* w_k = (const float*)d_in[3];
    const float* b_k = (const float*)d_in[4];
    const float* w_v = (const float*)d_in[5];
    const float* b_v = (const float*)d_in[6];
    const float* w_o = (const float*)d_in[7];
    const float* b_o = (const float*)d_in[8];
    float* out = (float*)d_out;

    char* ws = (char*)d_ws;
    u16* xb  = (u16*)(ws);                        // 16 MB (16384,512) bf16
    u16* xp  = (u16*)(ws + (16ull << 20));        //  4 MB (4096,512)
    u16* Qw  = (u16*)(ws + (20ull << 20));        // 16 MB (16384,512)
    u16* Kw  = (u16*)(ws + (36ull << 20));        //  4 MB (4096,512)
    u16* VwT = (u16*)(ws + (40ull << 20));        //  4 MB 32x(64,1024)
    u16* wT  = (u16*)(ws + (44ull << 20));        //  2 MB: 4 x 512x512 bf16
    u16* Ow  = xb;  // alias: xb's last reader (Q-GEMM) precedes attn's write

    cvt_kernel<<<8192, 256, 0, stream>>>(x, xb);
    wtrans_kernel<<<dim3(8, 8, 4), 256, 0, stream>>>(w_q, w_k, w_v, w_o, wT);
    pool_kernel<<<1024, 256, 0, stream>>>(xb, xp);
    // Q projection (scaled by log2(e)/8): 4 n-blocks x 256 m-blocks
    gemm_bf16<0><<<dim3(4, 256), 256, 0, stream>>>(xb, wT, b_q, nullptr, Qw, nullptr, QSCALE);
    // fused K|V projection (N=1024): 8 n-blocks x 64 m-blocks
    gemm_bf16<3><<<dim3(8, 64), 256, 0, stream>>>(xp, wT + 262144, b_k, b_v, Kw, VwT, 1.0f);
    // attention: 32 groups (x: XCD-pinned) x 32 q-tiles (y)
    attn_kernel<<<dim3(32, 32), 256, 0, stream>>>(Qw, Kw, VwT, Ow);
    // output projection + f32 residual: 4 x 256
    gemm_bf16<1><<<dim3(4, 256), 256, 0, stream>>>(Ow, wT + 786432, b_o, x, out, nullptr, 1.0f);
}

// Round 6
// 196.753 us; speedup vs baseline: 1.2679x; 1.0190x over previous
//
#include <hip/hip_runtime.h>
#include <hip/hip_bf16.h>
#include <math.h>

typedef short bf16x8 __attribute__((ext_vector_type(8)));
typedef float f32x4 __attribute__((ext_vector_type(4)));
typedef unsigned short u16;

__device__ inline float b2f(u16 h) {
    unsigned int u = ((unsigned int)h) << 16;
    float f;
    __builtin_memcpy(&f, &u, 4);
    return f;
}

__device__ inline u16 f2b(float f) {
    unsigned int u;
    __builtin_memcpy(&u, &f, 4);
    unsigned int lsb = (u >> 16) & 1u;
    u += 0x7fffu + lsb;
    return (u16)(u >> 16);
}

// async 16B global -> LDS (wave-uniform base + lane*16 at all call sites)
__device__ __forceinline__ void gl2lds16(const u16* g, u16* l) {
    __builtin_amdgcn_global_load_lds(
        (const __attribute__((address_space(1))) unsigned int*)g,
        (__attribute__((address_space(3))) unsigned int*)l,
        16, 0, 0);
}

#define PITCH 72   // wtrans scratch pitch

// log2(e) / 8  (softmax temperature sqrt(64)=8 folded into Q projection)
#define QSCALE 0.18033688011112042f

// ---------------------------------------------------------------------------
// Launch 1: cvt (blocks 0..8191) U wtrans (blocks 8192..8447).
// Independent inputs -> one launch, no inter-stage bubble.
// ---------------------------------------------------------------------------
__global__ __launch_bounds__(256) void cvtw_kernel(const float* __restrict__ x,
                                                   u16* __restrict__ xb,
                                                   const float* __restrict__ w0,
                                                   const float* __restrict__ w1,
                                                   const float* __restrict__ w2,
                                                   const float* __restrict__ w3,
                                                   u16* __restrict__ wt) {
    __shared__ u16 T[64 * PITCH];
    int tid = threadIdx.x;
    if (blockIdx.x < 8192) {            // ---- cvt: x f32 -> bf16
        int idx = blockIdx.x * 256 + tid;   // 2,097,152 float4s
        float4 v = ((const float4*)x)[idx];
        ushort4 o;
        o.x = f2b(v.x); o.y = f2b(v.y); o.z = f2b(v.z); o.w = f2b(v.w);
        ((ushort4*)xb)[idx] = o;
        return;
    }
    // ---- wtrans: transpose+convert four 512x512 f32 weights to WT[n][k]
    int t5 = blockIdx.x - 8192;         // 0..255
    int bx = t5 & 7, by = (t5 >> 3) & 7, bz = t5 >> 6;
    const float* W = bz == 0 ? w0 : bz == 1 ? w1 : bz == 2 ? w2 : w3;
    u16* WT = wt + (size_t)bz * 262144;
    int nB = bx * 64, kB = by * 64;
#pragma unroll
    for (int t = 0; t < 4; ++t) {
        int e = tid + t * 256;
        int r = e >> 4, c4 = (e & 15) * 4;
        float4 v = *(const float4*)(&W[(size_t)(kB + r) * 512 + nB + c4]);
        u16* dst = &T[r * PITCH + c4];
        dst[0] = f2b(v.x); dst[1] = f2b(v.y); dst[2] = f2b(v.z); dst[3] = f2b(v.w);
    }
    __syncthreads();
    int n = tid & 63, kg = tid >> 6;
#pragma unroll
    for (int p = 0; p < 2; ++p) {
        int k0 = (kg + p * 4) * 8;
        u16 tmp[8];
#pragma unroll
        for (int i = 0; i < 8; ++i) tmp[i] = T[(k0 + i) * PITCH + n];
        *(int4*)(&WT[(size_t)(nB + n) * 512 + kB + k0]) = *(int4*)tmp;
    }
}

// ---------------------------------------------------------------------------
// pool body: TF avg-pool 3x3/s2 SAME (divide by valid count), bf16 in/out.
// ---------------------------------------------------------------------------
__device__ __forceinline__ void pool_body(int idx, const u16* __restrict__ xb,
                                          u16* __restrict__ xp) {
    int c8 = idx & 63;
    int j = (idx >> 6) & 31;
    int i = (idx >> 11) & 31;
    int b = idx >> 16;
    int r0 = 2 * i, c0 = 2 * j;
    int rmax = min(r0 + 3, 64), cmax = min(c0 + 3, 64);
    float acc[8] = {};
    for (int r = r0; r < rmax; ++r)
        for (int cc = c0; cc < cmax; ++cc) {
            bf16x8 v = *(const bf16x8*)(
                &xb[(size_t)((((b << 6) + r) << 6) + cc) * 512 + c8 * 8]);
#pragma unroll
            for (int t = 0; t < 8; ++t) acc[t] += b2f(((const u16*)&v)[t]);
        }
    float inv = 1.f / (float)((rmax - r0) * (cmax - c0));
    u16 o[8];
#pragma unroll
    for (int t = 0; t < 8; ++t) o[t] = f2b(acc[t] * inv);
    *(int4*)(&xp[(size_t)idx * 8]) = *(int4*)o;
}

// ---------------------------------------------------------------------------
// GEMM body: tile 64xBN (BN=128 or 64), BK=64, 4 waves. BN=128: 2x2 waves,
// wave 32x64, acc[2][4]. BN=64: 4x1 waves, wave 16x64, acc[1][4].
// global_load_lds into XOR-8 swizzled LDS; 4/CU occupancy (round-4/5 A/B:
// grid-limited occupancy was the GEMM bottleneck).
// XCD remap: bid = nBlk*GY + mBlk, GY % 8 == 0 -> A-panel sharers (same mBlk,
// all nBlk) land on one XCD's L2 (round-4 win).
// OM=0: bf16 * oscale. OM=1: f32 + residual. OM=3: fused K|V split at col 512.
// ---------------------------------------------------------------------------
template <int OM, int BN, int GY>
__device__ __forceinline__ void gemm_body(int bid,
                                          const u16* __restrict__ A,
                                          const u16* __restrict__ WT,
                                          const float* __restrict__ bias,
                                          const float* __restrict__ bias2res,
                                          void* __restrict__ Cv,
                                          void* __restrict__ Cv2,
                                          float oscale,
                                          u16* At, u16* Bt) {
    int tid = threadIdx.x, lane = tid & 63, wave = tid >> 6;
    int q = lane >> 4, l16 = lane & 15;
    constexpr int MI = (BN == 128) ? 2 : 1;
    int wm, wn;
    if constexpr (BN == 128) { wm = wave & 1; wn = wave >> 1; }
    else                     { wm = wave;     wn = 0; }
    int nBlk = bid / GY;
    int mBlk = bid - nBlk * GY;
    int nBase = nBlk * BN, mBase = mBlk * 64;
    f32x4 acc[MI][4] = {};

    for (int kk = 0; kk < 512; kk += 64) {
        __syncthreads();
#pragma unroll
        for (int t = 0; t < 2; ++t) {             // At: 512 chunk slots
            int c = tid + t * 256;
            int m = c >> 3, kc = (c & 7) ^ (m & 7);
            gl2lds16(&A[(size_t)(mBase + m) * 512 + kk + kc * 8], &At[c * 8]);
        }
#pragma unroll
        for (int t = 0; t < BN / 32; ++t) {       // Bt: BN*8 chunk slots
            int c = tid + t * 256;
            int m = c >> 3, kc = (c & 7) ^ (m & 7);
            gl2lds16(&WT[(size_t)(nBase + m) * 512 + kk + kc * 8], &Bt[c * 8]);
        }
        __syncthreads();
#pragma unroll
        for (int ds = 0; ds < 2; ++ds) {
            bf16x8 a[MI], b[4];
#pragma unroll
            for (int i = 0; i < MI; ++i) {
                int ma = (BN == 128 ? wm * 32 : wm * 16) + i * 16 + l16;
                a[i] = *(bf16x8*)(&At[ma * 64 + ((((ds << 2) + q) ^ (ma & 7)) << 3)]);
            }
#pragma unroll
            for (int j = 0; j < 4; ++j) {
                int nb = wn * 64 + j * 16 + l16;
                b[j] = *(bf16x8*)(&Bt[nb * 64 + ((((ds << 2) + q) ^ (nb & 7)) << 3)]);
            }
#pragma unroll
            for (int i = 0; i < MI; ++i)
#pragma unroll
                for (int j = 0; j < 4; ++j)
                    acc[i][j] = __builtin_amdgcn_mfma_f32_16x16x32_bf16(a[i], b[j], acc[i][j], 0, 0, 0);
        }
    }

    bool isK = (OM != 3) || (nBase < 512);
#pragma unroll
    for (int j = 0; j < 4; ++j) {
        int col = nBase + wn * 64 + j * 16 + l16;
        float bv;
        if constexpr (OM == 3) bv = isK ? bias[col] : bias2res[col - 512];
        else bv = bias[col];
#pragma unroll
        for (int i = 0; i < MI; ++i) {
#pragma unroll
            for (int r = 0; r < 4; ++r) {
                int row = mBase + (BN == 128 ? wm * 32 : wm * 16) + i * 16 + q * 4 + r;
                float v = acc[i][j][r] + bv;
                if constexpr (OM == 1) {
                    v += bias2res[(size_t)row * 512 + col];
                    ((float*)Cv)[(size_t)row * 512 + col] = v;
                } else if constexpr (OM == 0) {
                    ((u16*)Cv)[(size_t)row * 512 + col] = f2b(v * oscale);
                } else {
                    if (isK) {
                        ((u16*)Cv)[(size_t)row * 512 + col] = f2b(v);
                    } else {
                        int colv = col - 512;
                        int g = row >> 7, m2 = ((row & 127) << 3) + (colv >> 6), d = colv & 63;
                        ((u16*)Cv2)[(size_t)((g << 6) + d) * 1024 + m2] = f2b(v);
                    }
                }
            }
        }
    }
}

// ---------------------------------------------------------------------------
// Launch 2: Q-GEMM (blocks 0..1023) U pool (blocks 1024..2047). Both depend
// only on cvt's xb; pool's mem-bound blocks fill the machine while GEMM
// blocks stage/drain. Block-uniform branch; LDS = GEMM's 24 KB.
// ---------------------------------------------------------------------------
__global__ __launch_bounds__(256, 4) void qpool_kernel(const u16* __restrict__ xb,
                                                       const u16* __restrict__ wTq,
                                                       const float* __restrict__ b_q,
                                                       u16* __restrict__ Qw,
                                                       u16* __restrict__ xp) {
    __shared__ __align__(16) u16 At[64 * 64];
    __shared__ __align__(16) u16 Bt[128 * 64];
    int gid = blockIdx.x;
    if (gid < 1024) {
        gemm_body<0, 128, 256>(gid, xb, wTq, b_q, nullptr, Qw, nullptr, QSCALE, At, Bt);
    } else {
        pool_body((gid - 1024) * 256 + threadIdx.x, xb, xp);
    }
}

// Launch 3: fused K|V projection, tile 64x64 -> 1024 blocks = 4/CU
// (was 512 blocks = 2/CU: the exact grid-limited-occupancy condition the
// round-4/5 A/B proved costly for Q/O).
__global__ __launch_bounds__(256, 4) void gemm_kv_kernel(const u16* __restrict__ xp,
                                                         const u16* __restrict__ wTkv,
                                                         const float* __restrict__ b_k,
                                                         const float* __restrict__ b_v,
                                                         u16* __restrict__ Kw,
                                                         u16* __restrict__ VwT) {
    __shared__ __align__(16) u16 At[64 * 64];
    __shared__ __align__(16) u16 Bt[64 * 64];
    gemm_body<3, 64, 64>(blockIdx.x, xp, wTkv, b_k, b_v, Kw, VwT, 1.0f, At, Bt);
}

// Launch 5: output projection + f32 residual.
__global__ __launch_bounds__(256, 4) void gemm_o_kernel(const u16* __restrict__ Ow,
                                                        const u16* __restrict__ wTo,
                                                        const float* __restrict__ b_o,
                                                        const float* __restrict__ xres,
                                                        float* __restrict__ out) {
    __shared__ __align__(16) u16 At[64 * 64];
    __shared__ __align__(16) u16 Bt[128 * 64];
    gemm_body<1, 128, 256>(blockIdx.x, Ow, wTo, b_o, xres, out, nullptr, 1.0f, At, Bt);
}

// ---------------------------------------------------------------------------
// Launch 4: flash attention per group, S^T formulation.
// Harness-verified single-buffer structure; VALU cut (exp2 builtin + cvt_pk);
// XCD pinning (g = blockIdx.x -> XCD = g&7; FETCH 41->12 MB confirmed);
// s_setprio(1) around MFMA clusters. LDS 40960 B -> 4 blocks/CU; grid 1024.
// ---------------------------------------------------------------------------
__global__ __launch_bounds__(256, 4) void attn_kernel(const u16* __restrict__ Q,
                                                      const u16* __restrict__ K,
                                                      const u16* __restrict__ VT_g,
                                                      u16* __restrict__ O) {
    int g = blockIdx.x;       // XCD = g & 7 (round-robin by linear id)
    int qtile = blockIdx.y;   // 0..31
    const u16* Qg = Q + (size_t)g * 262144;
    const u16* Kg = K + (size_t)g * 65536;
    const u16* Vt = VT_g + (size_t)g * 65536;   // [d][m], pitch 1024
    u16* Og = O + (size_t)g * 262144;

    __shared__ __align__(16) u16 Kt[128 * 64];    // XOR-8 swizzled [m][d]
    __shared__ __align__(16) u16 VTs[64 * 128];   // XOR-16 swizzled [d][m]
    __shared__ __align__(16) u16 Pt[64 * 64];     // XOR-4dw swizzled [n][m-half]

    int tid = threadIdx.x, lane = tid & 63, wave = tid >> 6;
    int q = lane >> 4, l16 = lane & 15;
    int n0 = qtile * 128;
    int pkey = (l16 & 7) << 2;            // dword-XOR key for Pt
    int prow = (wave * 16 + l16) * 32;    // Pt row base (dwords)
    int* Pt32 = (int*)Pt;

    bf16x8 qf[2][2];
#pragma unroll
    for (int s = 0; s < 2; ++s)
#pragma unroll
        for (int ds = 0; ds < 2; ++ds)
            qf[s][ds] = *(const bf16x8*)(
                &Qg[(size_t)(n0 + s * 64 + wave * 16 + l16) * 64 + ds * 32 + q * 8]);

    f32x4 oacc[2][4] = {};
    float rsum[2] = {0.f, 0.f};

    for (int kb = 0; kb < 8; ++kb) {
        __syncthreads();
#pragma unroll
        for (int t = 0; t < 4; ++t) {
            int c = wave * 64 + lane + t * 256;       // slot 0..1023
            {   // K tile: 128 m-rows x 64 d, XOR-8
                int m = c >> 3, kc = (c & 7) ^ (m & 7);
                gl2lds16(&Kg[(size_t)(kb * 128 + m) * 64 + kc * 8], &Kt[c * 8]);
            }
            {   // V^T tile: 64 d-rows x 128 m, XOR-16
                int d = c >> 4, mc = (c & 15) ^ (d & 15);
                gl2lds16(&Vt[(size_t)d * 1024 + kb * 128 + mc * 8], &VTs[c * 8]);
            }
        }
        __syncthreads();

#pragma unroll
        for (int h = 0; h < 2; ++h) {
#pragma unroll
            for (int s = 0; s < 2; ++s) {
                // S^T block; p = exp2(z); packed b64 write to Pt[n][m]
#pragma unroll
                for (int cb = 0; cb < 4; ++cb) {
                    int m = h * 64 + cb * 16 + l16;
                    bf16x8 kf0 = *(bf16x8*)(&Kt[m * 64 + ((q ^ (m & 7)) << 3)]);
                    bf16x8 kf1 = *(bf16x8*)(&Kt[m * 64 + (((4 + q) ^ (m & 7)) << 3)]);
                    f32x4 z = {};
                    __builtin_amdgcn_s_setprio(1);
                    z = __builtin_amdgcn_mfma_f32_16x16x32_bf16(kf0, qf[s][0], z, 0, 0, 0);
                    z = __builtin_amdgcn_mfma_f32_16x16x32_bf16(kf1, qf[s][1], z, 0, 0, 0);
                    __builtin_amdgcn_s_setprio(0);
                    float p0 = __builtin_amdgcn_exp2f(z[0]);
                    float p1 = __builtin_amdgcn_exp2f(z[1]);
                    float p2 = __builtin_amdgcn_exp2f(z[2]);
                    float p3 = __builtin_amdgcn_exp2f(z[3]);
                    rsum[s] += (p0 + p1) + (p2 + p3);
                    unsigned w0, w1;
                    asm("v_cvt_pk_bf16_f32 %0, %1, %2" : "=v"(w0) : "v"(p0), "v"(p1));
                    asm("v_cvt_pk_bf16_f32 %0, %1, %2" : "=v"(w1) : "v"(p2), "v"(p3));
                    int2 w;
                    w.x = (int)w0;
                    w.y = (int)w1;
                    int pd = (cb * 8 + q * 2) ^ pkey;
                    *(int2*)(&Pt32[prow + pd]) = w;
                }
                // O += P V (same wave wrote Pt rows; DS in-order, no barrier)
#pragma unroll
                for (int ds = 0; ds < 2; ++ds) {
                    int pd = (ds * 16 + q * 4) ^ pkey;
                    bf16x8 ap = *(bf16x8*)(&Pt32[prow + pd]);
                    __builtin_amdgcn_s_setprio(1);
#pragma unroll
                    for (int db = 0; db < 4; ++db) {
                        int dd = db * 16 + l16;
                        int jj = h * 8 + ds * 4 + q;
                        bf16x8 vb = *(bf16x8*)(&VTs[dd * 128 + ((jj ^ (dd & 15)) << 3)]);
                        oacc[s][db] = __builtin_amdgcn_mfma_f32_16x16x32_bf16(ap, vb, oacc[s][db], 0, 0, 0);
                    }
                    __builtin_amdgcn_s_setprio(0);
                }
            }
        }
    }

    // epilogue: rsum lives at row n=l16 (partial over quads) -> reduce over
    // quads, then fetch row (q*4+r)'s total via shfl, normalize, store.
#pragma unroll
    for (int s = 0; s < 2; ++s) {
        float v = rsum[s];
        v += __shfl_xor(v, 16, 64);
        v += __shfl_xor(v, 32, 64);
        rsum[s] = v;
    }
    float inv[2][4];
#pragma unroll
    for (int s = 0; s < 2; ++s)
#pragma unroll
        for (int r = 0; r < 4; ++r)
            inv[s][r] = 1.f / __shfl(rsum[s], q * 4 + r, 64);
#pragma unroll
    for (int s = 0; s < 2; ++s)
#pragma unroll
        for (int db = 0; db < 4; ++db)
#pragma unroll
            for (int r = 0; r < 4; ++r) {
                int row = n0 + s * 64 + wave * 16 + q * 4 + r;
                Og[(size_t)row * 64 + db * 16 + l16] = f2b(oacc[s][db][r] * inv[s][r]);
            }
}

// ---------------------------------------------------------------------------
extern "C" void kernel_launch(void* const* d_in, const int* in_sizes, int n_in,
                              void* d_out, int out_size, void* d_ws, size_t ws_size,
                              hipStream_t stream) {
    const float* x   = (const float*)d_in[0];
    const float* w_q = (const float*)d_in[1];
    const float* b_q = (const float*)d_in[2];
    const float* w_k = (const float*)d_in[3];
    const float* b_k = (const float*)d_in[4];
    const float* w_v = (const float*)d_in[5];
    const float* b_v = (const float*)d_in[6];
    const float* w_o = (const float*)d_in[7];
    const float* b_o = (const float*)d_in[8];
    float* out = (float*)d_out;

    char* ws = (char*)d_ws;
    u16* xb  = (u16*)(ws);                        // 16 MB (16384,512) bf16
    u16* xp  = (u16*)(ws + (16ull << 20));        //  4 MB (4096,512)
    u16* Qw  = (u16*)(ws + (20ull << 20));        // 16 MB (16384,512)
    u16* Kw  = (u16*)(ws + (36ull << 20));        //  4 MB (4096,512)
    u16* VwT = (u16*)(ws + (40ull << 20));        //  4 MB 32x(64,1024)
    u16* wT  = (u16*)(ws + (44ull << 20));        //  2 MB: 4 x 512x512 bf16
    u16* Ow  = xb;  // alias: xb's last readers (Q-GEMM+pool, L2) precede attn's write (L4)

    // L1: cvt U wtrans
    cvtw_kernel<<<8448, 256, 0, stream>>>(x, xb, w_q, w_k, w_v, w_o, wT);
    // L2: Q projection (scaled by log2(e)/8) U pool
    qpool_kernel<<<2048, 256, 0, stream>>>(xb, wT, b_q, Qw, xp);
    // L3: fused K|V projection, 16 n-blocks x 64 m-blocks
    gemm_kv_kernel<<<1024, 256, 0, stream>>>(xp, wT + 262144, b_k, b_v, Kw, VwT);
    // L4: attention: 32 groups (x: XCD-pinned) x 32 q-tiles (y)
    attn_kernel<<<dim3(32, 32), 256, 0, stream>>>(Qw, Kw, VwT, Ow);
    // L5: output projection + f32 residual
    gemm_o_kernel<<<1024, 256, 0, stream>>>(Ow, wT + 786432, b_o, x, out);
}